// Round 11
// baseline (136.161 us; speedup 1.0000x reference)
//
#include <hip/hip_runtime.h>

// B=16, L=2048, V=64.
// Algebraic reduction (e is one-hot):
//   E[d] = exp(v_emb[d]); S[t] = prefix_sum(E)[t]
//   F[b,c,s] = sum_{k<=s} E[s-k] * Wq[idx[b,k], c]            (causal Toeplitz GEMM)
//   P[b,c,s] = exp(F[b,c,s] / S[s])                           (softmax w/o max; scores tiny)
//   out[b,t,v] = Wv00 * (sum_{s<=t, idx[b,s]==v} P[b,c_t,s]) / (sum_{s<=t} P[b,c_t,s]),  c_t = idx[b,t]
//
// R26: R25 split = 117.5 (best), but k1 is LDS-gather bound AND CU-imbalanced
// (1 tile/block: 2x per-CU work variance), plus a k1->k2 launch gap. Re-merge
// into ONE kernel, grid=512: each block runs the R16-verified tile PAIR
// (bn=63-jj, jj) -> exactly 66 k-units/block (perfect balance, ~zero barrier
// skew), setup staged once, no second launch. Sync = R22-verified fence-free
// sc1 batch barrier (BPB=32). Fragility fixed: grid 512 vs capacity >=1024
// (4/CU bounds, 29.7KB LDS) -> all blocks resident with 2x slack; R24's
// 31ms replay outlier structurally impossible. Predicted k_fused 38-48us,
// total 95-108, no outliers.

#define LSEQ 2048
#define NB 16
#define NV 64
#define NC 32             // 32 chunks of 64
#define NBLK 512          // fused grid size
#define BPB 32            // blocks per batch

typedef __attribute__((ext_vector_type(8))) short bf16x8;
typedef __attribute__((ext_vector_type(4))) float f32x4;

__device__ __forceinline__ unsigned short f2bf(float f) {   // RNE float->bf16
  unsigned int u = __float_as_uint(f);
  return (unsigned short)((u + 0x7FFFu + ((u >> 16) & 1u)) >> 16);
}

// ---- per-batch barrier, FENCE-FREE (verified R22/R23/R24) ---------------
__device__ __forceinline__ void bb_arrive(unsigned int* cnt, unsigned int* flag) {
  __syncthreads();
  if (threadIdx.x == 0) {
    unsigned int old = __hip_atomic_fetch_add(cnt, 1u, __ATOMIC_RELAXED,
                                              __HIP_MEMORY_SCOPE_AGENT);
    if (old == BPB - 1u)
      __hip_atomic_store(flag, 1u, __ATOMIC_RELAXED, __HIP_MEMORY_SCOPE_AGENT);
  }
}
__device__ __forceinline__ void bb_wait(unsigned int* flag) {
  if (threadIdx.x == 0) {
    while (__hip_atomic_load(flag, __ATOMIC_RELAXED,
                             __HIP_MEMORY_SCOPE_AGENT) == 0u)
      __builtin_amdgcn_s_sleep(2);
  }
  __syncthreads();
}

// =====================================================================
// Fused kernel, grid=512, plain launch (2/CU vs capacity 4/CU):
// setup once | GEMM tile pair (66 k-units/block, balanced) | sc1 P |
// batchbar | phase2 scan+emit (2 (b,c)/block).
// =====================================================================
__global__ __launch_bounds__(256, 4) void k_fused(
    const int* __restrict__ idx, const float* __restrict__ Wq,
    const float* __restrict__ Wv, const float* __restrict__ v_emb,
    float* __restrict__ P, float* __restrict__ out,
    unsigned int* __restrict__ bar) {
  union SMem {
    struct {  // setup + GEMM
      unsigned short Wqb[64 * 65];  // bf16 Wq, padded rows (8320B)
      unsigned short ro[2048];      // ro[i] = idx[b,2047-i]*65 (4096B)
      unsigned short GL0[2208];     // GL0[i] = (127<=i<2175) ? E[i-127] : 0
      unsigned short GL1[2176];     // GL1[i] = GLv(i+1)
      float red[16][64];
      float red2[16][64];
      float Spart2[2][32];          // S over both tiles' n-ranges
      float swsum[4];
    } g;
    struct {  // phase 2 (scan+emit)
      float Hs[NC][65];
      float pl[4][64];
      unsigned long long mk[4][64];
    } s;
  };
  __shared__ SMem sm;

  const int bid = blockIdx.x;     // [0, 512)
  const int tid = threadIdx.x;
  const int w = tid >> 6;
  const int lane = tid & 63;
  const int b = bid >> 5;         // batch; 32 blocks per batch
  const int jj = bid & 31;        // pair (bn=63-jj heavy, bn=jj light)

  unsigned int* cntb  = bar +   0 + b * 32;
  unsigned int* flagb = bar + 512 + b * 32;

  const int quad = lane >> 4;
  const int lm = lane & 15;
  const int nsub = w & 1;                  // n-offset 0 / 16
  const int kh = w >> 1;                   // k-half 0 / 1
  const int n0a = (63 - jj) * 32;          // heavy tile n-range
  const int n0b = jj * 32;                 // light tile n-range

  // ---------------- setup (once): Wq -> LDS bf16, ro, E/S -------------
  {
#pragma unroll
    for (int u = 0; u < 16; ++u) {
      const int e = tid * 16 + u;          // [0,4096)
      sm.g.Wqb[(e >> 6) * 65 + (e & 63)] = f2bf(Wq[e]);
    }
#pragma unroll
    for (int j = 0; j < 8; ++j) {
      const int t = tid * 8 + j;
      sm.g.ro[2047 - t] = (unsigned short)(idx[b * LSEQ + t] * 65);
    }
    float ev[8], ps8[8];
    float tot = 0.f;
    const int t0 = tid * 8;
#pragma unroll
    for (int j = 0; j < 8; ++j) {
      const float e = expf(v_emb[t0 + j]);
      tot += e; ev[j] = e; ps8[j] = tot;
    }
    float ws = tot;                        // wave-inclusive scan of thread sums
#pragma unroll
    for (int d = 1; d < 64; d <<= 1) {
      float up = __shfl_up(ws, d);
      if (lane >= d) ws += up;
    }
    if (lane == 63) sm.g.swsum[w] = ws;
    __syncthreads();
    float wbase = 0.f;
#pragma unroll
    for (int k = 0; k < 4; ++k) if (k < w) wbase += sm.g.swsum[k];
    const float base = wbase + (ws - tot); // exclusive base for this thread
#pragma unroll
    for (int j = 0; j < 8; ++j) {
      const int d = t0 + j;
      const float Sv = base + ps8[j];
      if ((unsigned)(d - n0a) < 32u) sm.g.Spart2[0][d - n0a] = Sv;
      if ((unsigned)(d - n0b) < 32u) sm.g.Spart2[1][d - n0b] = Sv;
      const unsigned short bv = f2bf(ev[j]);
      sm.g.GL0[d + 127] = bv;              // GL0[i]=E[i-127]
      sm.g.GL1[d + 126] = bv;              // GL1[i]=E[i-126]
    }
    if (tid < 31) sm.g.GL0[96 + tid] = 0;  // zero [96,127)
    if (tid < 30) sm.g.GL1[96 + tid] = 0;  // zero [96,126)
    if (tid == 0) { sm.g.GL0[2175] = 0; sm.g.GL1[2174] = 0; sm.g.GL1[2175] = 0; }
    __syncthreads();                       // all LDS (Wqb/ro/GL/Spart2) ready
  }

  // ---------------- GEMM: two balanced tiles, block-local A-path ------
  {
// A-fragment from LDS: ro_b128 (quad-broadcast) + 32x ds_read_u16.
#define LOAD_FRAGS(J_, SL) do {                                             \
    const int k_ = kstart + (kh + 2 * (J_)) * 32;                           \
    const int i0_ = k_ + quad * 8;                                          \
    unsigned short ro_[8];                                                  \
    *(uint4*)ro_ = *(const uint4*)&sm.g.ro[i0_];                            \
_Pragma("unroll")                                                           \
    for (int j_ = 0; j_ < 8; ++j_) {                                        \
      const int base_ = (int)ro_[j_] + lm;                                  \
      a[SL][0].s[j_] = sm.g.Wqb[base_ +  0];                                \
      a[SL][1].s[j_] = sm.g.Wqb[base_ + 16];                                \
      a[SL][2].s[j_] = sm.g.Wqb[base_ + 32];                                \
      a[SL][3].s[j_] = sm.g.Wqb[base_ + 48];                                \
    }                                                                       \
    const int s_ = sbase + k_ + quad * 8;                                   \
    const unsigned int* gb_ = (s_ & 1) ? (const unsigned int*)sm.g.GL1      \
                                       : (const unsigned int*)sm.g.GL0;     \
    const int off_ = s_ >> 1;                                               \
    bb[SL].u[0] = gb_[off_ + 0]; bb[SL].u[1] = gb_[off_ + 1];               \
    bb[SL].u[2] = gb_[off_ + 2]; bb[SL].u[3] = gb_[off_ + 3];               \
  } while (0)

#define MFMA4(SL) do {                                                      \
    acc[0] = __builtin_amdgcn_mfma_f32_16x16x32_bf16(a[SL][0].v, bb[SL].v, acc[0], 0, 0, 0); \
    acc[1] = __builtin_amdgcn_mfma_f32_16x16x32_bf16(a[SL][1].v, bb[SL].v, acc[1], 0, 0, 0); \
    acc[2] = __builtin_amdgcn_mfma_f32_16x16x32_bf16(a[SL][2].v, bb[SL].v, acc[2], 0, 0, 0); \
    acc[3] = __builtin_amdgcn_mfma_f32_16x16x32_bf16(a[SL][3].v, bb[SL].v, acc[3], 0, 0, 0); \
  } while (0)

    for (int half = 0; half < 2; ++half) {
      const int bn = half ? jj : (63 - jj);
      const int n0 = bn * 32;
      const int nbase = n0 + nsub * 16;
      const int sbase = nbase + lm - 1920;
      const int kstart = 2048 - (n0 + 32);   // multiple of 32
      const int iters = bn + 1;              // 32-k steps for this tile

      f32x4 acc[4];
#pragma unroll
      for (int mt = 0; mt < 4; ++mt) acc[mt] = (f32x4){0.f, 0.f, 0.f, 0.f};

      union AF { unsigned short s[8]; bf16x8 v; };
      union BF { unsigned int u[4]; bf16x8 v; };
      AF a[3][4];
      BF bb[3];

      const int J = (iters > kh) ? ((iters - kh + 1) >> 1) : 0;  // wave-iters
      if (J > 0) {
        LOAD_FRAGS(0, 0);
        if (J > 1) LOAD_FRAGS(1, 1);
        int j = 0;
        while (true) {
          if (j + 2 < J) LOAD_FRAGS(j + 2, 2);
          MFMA4(0);
          if (++j >= J) break;
          if (j + 2 < J) LOAD_FRAGS(j + 2, 0);
          MFMA4(1);
          if (++j >= J) break;
          if (j + 2 < J) LOAD_FRAGS(j + 2, 1);
          MFMA4(2);
          if (++j >= J) break;
        }
      }

      // reduce k-half 1 into k-half 0 via LDS
      if (kh == 1) {
        float (*rd)[64] = nsub ? sm.g.red2 : sm.g.red;
#pragma unroll
        for (int mt = 0; mt < 4; ++mt)
#pragma unroll
          for (int r = 0; r < 4; ++r) rd[mt * 4 + r][lane] = acc[mt][r];
      }
      __syncthreads();
      if (kh == 0) {
        float (*rd)[64] = nsub ? sm.g.red2 : sm.g.red;
#pragma unroll
        for (int mt = 0; mt < 4; ++mt)
#pragma unroll
          for (int r = 0; r < 4; ++r) acc[mt][r] += rd[mt * 4 + r][lane];

        // epilogue: C/D layout col(s)=lm, row(c)=quad*4+r; sc1 P stores
        const float sinv = 1.0f / sm.g.Spart2[half][nsub * 16 + lm];
#pragma unroll
        for (int mt = 0; mt < 4; ++mt) {
#pragma unroll
          for (int r = 0; r < 4; ++r) {
            const int c = mt * 16 + quad * 4 + r;
            const float val = __expf(acc[mt][r] * sinv);
            __hip_atomic_store(&P[((size_t)(b * 64 + c)) * LSEQ + nbase + lm],
                               val, __ATOMIC_RELAXED, __HIP_MEMORY_SCOPE_AGENT);
          }
        }
      }
      __syncthreads();   // protect red/red2 reuse by the second tile
    }
#undef LOAD_FRAGS
#undef MFMA4
  }
  bb_arrive(cntb, flagb);          // both tiles' P columns complete

  // ---------------- phase 2: hists + scan + fence-free emission -------
  {
    const int* __restrict__ irow = idx + b * LSEQ;
    int ii[8];
#pragma unroll
    for (int r = 0; r < 8; ++r)    // idx-only loads: overlap the wait
      ii[r] = irow[(w * 8 + r) * 64 + lane];

    bb_wait(flagb);                // all of batch b's P rows ready

    const float wv = Wv[0];
    for (int q = 0; q < 2; ++q) {
      const int bc = (bid << 1) | q;   // [0, 1024); (bc>>6) == b
      const int c = bc & 63;
      const float* __restrict__ prow = P + (size_t)bc * LSEQ;

      float p[8];
#pragma unroll
      for (int r = 0; r < 8; ++r)    // coherent sc1 loads
        p[r] = __hip_atomic_load(prow + (w * 8 + r) * 64 + lane,
                                 __ATOMIC_RELAXED, __HIP_MEMORY_SCOPE_AGENT);

      __syncthreads();               // protect Hs (union w/ red; prior q)
      for (int i = tid; i < NC * 65; i += 256) ((float*)sm.s.Hs)[i] = 0.f;
      __syncthreads();
#pragma unroll
      for (int r = 0; r < 8; ++r) atomicAdd(&sm.s.Hs[w * 8 + r][ii[r]], p[r]);
      __syncthreads();

      // exclusive scan across chunks, per bin: 2 bins per pass
      const int hhalf = lane >> 5, l32 = lane & 31;
#pragma unroll
      for (int r = 0; r < 8; ++r) {
        const int v = w * 16 + r * 2 + hhalf;
        const float h = sm.s.Hs[l32][v];
        float x = h;
#pragma unroll
        for (int d = 1; d < 32; d <<= 1) {
          float up = __shfl_up(x, d, 32);
          if (l32 >= d) x += up;
        }
        sm.s.Hs[l32][v] = x - h;     // exclusive
      }
      __syncthreads();

#pragma unroll
      for (int r = 0; r < 8; ++r) {
        const int ch = w * 8 + r;
        unsigned long long em = __ballot(ii[r] == c);   // emission points
        if (em == 0ull) continue;                       // wave-uniform skip
        sm.s.pl[w][lane] = p[r];                        // stage p
        sm.s.mk[w][lane] = 0ull;
        atomicOr(&sm.s.mk[w][ii[r]], 1ull << lane);     // bin <- source lanes
        float ps = p[r];                                // within-chunk prefix
#pragma unroll
        for (int d = 1; d < 64; d <<= 1) {
          float up = __shfl_up(ps, d);
          if (lane >= d) ps += up;
        }
        const float hbase = sm.s.Hs[ch][lane];
        float zex = hbase;                              // Z_excl = sum_v Hs
#pragma unroll
        for (int d = 1; d < 64; d <<= 1) zex += __shfl_xor(zex, d);
        const unsigned long long myMask = sm.s.mk[w][lane];
        while (em) {
          const int srel = __builtin_ctzll(em);
          em &= em - 1;
          unsigned long long mm = myMask &
              ((srel == 63) ? ~0ull : ((1ull << (srel + 1)) - 1ull));
          float B = hbase;                              // bin value at this t
          while (mm) { const int l = __builtin_ctzll(mm); mm &= mm - 1; B += sm.s.pl[w][l]; }
          const float z = zex + __shfl(ps, srel);       // denominator
          out[((size_t)(b * LSEQ + ch * 64 + srel)) * 64 + lane] = wv * B / z;
        }
      }
    }
  }
}

extern "C" void kernel_launch(void* const* d_in, const int* in_sizes, int n_in,
                              void* d_out, int out_size, void* d_ws, size_t ws_size,
                              hipStream_t stream) {
  const int* idx     = (const int*)d_in[0];     // [16, 2048]
  const float* Wq    = (const float*)d_in[1];   // [64, 64]
  const float* Wv    = (const float*)d_in[2];   // [64, 64] (only [0,0] used)
  const float* v_emb = (const float*)d_in[3];   // [2048, 1]
  float* out = (float*)d_out;                   // [16, 2048, 64] fp32

  // workspace: [2048 f32 pad] | P[1024*2048] f32 | sync region at +16MB
  float* P = (float*)d_ws + LSEQ;
  unsigned int* bar = (unsigned int*)((char*)d_ws + (16u << 20));

  hipMemsetAsync(bar, 0, 8192, stream);   // zero cnt/flag lines

  // Plain launch: 512 blocks = 2/CU vs capacity 4/CU -> all resident with
  // 2x slack; the per-batch spin barrier cannot deadlock or crawl.
  k_fused<<<dim3(NBLK), dim3(256), 0, stream>>>(idx, Wq, Wv, v_emb, P, out,
                                                bar);
}

// Round 12
// 107.686 us; speedup vs baseline: 1.2644x; 1.2644x over previous
//
#include <hip/hip_runtime.h>

// B=16, L=2048, V=64.
// Algebraic reduction (e is one-hot):
//   E[d] = exp(v_emb[d]); S[t] = prefix_sum(E)[t]
//   F[b,c,s] = sum_{k<=s} E[s-k] * Wq[idx[b,k], c]            (causal Toeplitz GEMM)
//   P[b,c,s] = exp(F[b,c,s] / S[s])                           (softmax w/o max; scores tiny)
//   out[b,t,v] = Wv00 * (sum_{s<=t, idx[b,s]==v} P[b,c_t,s]) / (sum_{s<=t} P[b,c_t,s]),  c_t = idx[b,t]
//
// R28: R26 pairing regressed (78us k_fused: balance gained but occupancy
// halved -> LDS-gather pipe starved). Root cause found for R25-k1's
// imbalance: CU = bid mod 256, slot = bid>>8, and bn = 63-(bid&63) is
// invariant under +256 -> every CU got 4 IDENTICAL-bn tiles (4x64 vs 4x1
// k-units; wall ~2x mean). The gather floor is ~28us/CU balanced (8448
// ds_read_u16 x ~8cyc), so balance is the whole game. This round: R25 split
// VERBATIM except k1's tile permutation — u=bid&255, v=bid>>8, t=u>>4,
// bn = {t, 31-t, 32+t, 63-t}[v] -> per-CU work = 130 k-units EXACTLY
// constant, bijective (b,bn) coverage. k2 untouched (uniform work).
// Predicted total 117.5 -> 104-112.

#define LSEQ 2048
#define NB 16
#define NV 64
#define NC 32             // 32 chunks of 64
#define NBLK 1024

typedef __attribute__((ext_vector_type(8))) short bf16x8;
typedef __attribute__((ext_vector_type(4))) float f32x4;

__device__ __forceinline__ unsigned short f2bf(float f) {   // RNE float->bf16
  unsigned int u = __float_as_uint(f);
  return (unsigned short)((u + 0x7FFFu + ((u >> 16) & 1u)) >> 16);
}

// =====================================================================
// K1: setup (Wq/ro/E/S in LDS) + causal-Toeplitz MFMA GEMM, 1 32-col
// tile per block; CU-balanced tile permutation. Normal L2 P stores.
// =====================================================================
__global__ __launch_bounds__(256, 4) void k_gemm(
    const int* __restrict__ idx, const float* __restrict__ Wq,
    const float* __restrict__ v_emb, float* __restrict__ P) {
  struct SMem {
    unsigned short Wqb[64 * 65];  // bf16 Wq, padded rows (8320B)
    unsigned short ro[2048];      // ro[i] = idx[b,2047-i]*65 (4096B)
    unsigned short GL0[2208];     // GL0[i] = (127<=i<2175) ? E[i-127] : 0
    unsigned short GL1[2176];     // GL1[i] = GLv(i+1)
    float red[16][64];
    float red2[16][64];
    float Spart[32];              // S[n0..n0+32) for this block's tile
    float swsum[4];
  };
  __shared__ SMem sm;

  const int bid = blockIdx.x;     // [0, 1024)
  const int tid = threadIdx.x;
  const int w = tid >> 6;
  const int lane = tid & 63;

  // CU-balanced permutation: CU = bid mod 256, slot v = bid>>8.
  // b = u&15, t = u>>4; bn = {t, 31-t, 32+t, 63-t}[v].
  // Per-CU work = (t+1)+(32-t)+(33+t)+(64-t) = 130 k-units, constant.
  const int u = bid & 255;
  const int v = bid >> 8;
  const int b = u & 15;
  const int t = u >> 4;
  const int bn = (v == 0) ? t : (v == 1) ? (31 - t) : (v == 2) ? (32 + t)
                                                              : (63 - t);
  const int n0 = bn * 32;
  const int quad = lane >> 4;
  const int lm = lane & 15;
  const int nsub = w & 1;                  // n-offset 0 / 16
  const int kh = w >> 1;                   // k-half 0 / 1
  const int nbase = n0 + nsub * 16;

  // ---------------- setup: Wq -> LDS bf16, ro, E/S --------------------
  {
#pragma unroll
    for (int uu = 0; uu < 16; ++uu) {
      const int e = tid * 16 + uu;         // [0,4096)
      sm.Wqb[(e >> 6) * 65 + (e & 63)] = f2bf(Wq[e]);
    }
#pragma unroll
    for (int j = 0; j < 8; ++j) {
      const int tt = tid * 8 + j;
      sm.ro[2047 - tt] = (unsigned short)(idx[b * LSEQ + tt] * 65);
    }
    float ev[8], ps8[8];
    float tot = 0.f;
    const int t0 = tid * 8;
#pragma unroll
    for (int j = 0; j < 8; ++j) {
      const float e = expf(v_emb[t0 + j]);
      tot += e; ev[j] = e; ps8[j] = tot;
    }
    float ws = tot;                        // wave-inclusive scan of thread sums
#pragma unroll
    for (int d = 1; d < 64; d <<= 1) {
      float up = __shfl_up(ws, d);
      if (lane >= d) ws += up;
    }
    if (lane == 63) sm.swsum[w] = ws;
    __syncthreads();
    float wbase = 0.f;
#pragma unroll
    for (int k = 0; k < 4; ++k) if (k < w) wbase += sm.swsum[k];
    const float base = wbase + (ws - tot); // exclusive base for this thread
#pragma unroll
    for (int j = 0; j < 8; ++j) {
      const int d = t0 + j;
      const float Sv = base + ps8[j];
      if ((unsigned)(d - n0) < 32u) sm.Spart[d - n0] = Sv;
      const unsigned short bv = f2bf(ev[j]);
      sm.GL0[d + 127] = bv;                // GL0[i]=E[i-127]
      sm.GL1[d + 126] = bv;                // GL1[i]=E[i-126]
    }
    if (tid < 31) sm.GL0[96 + tid] = 0;    // zero [96,127)
    if (tid < 30) sm.GL1[96 + tid] = 0;    // zero [96,126)
    if (tid == 0) { sm.GL0[2175] = 0; sm.GL1[2174] = 0; sm.GL1[2175] = 0; }
    __syncthreads();                       // all LDS (Wqb/ro/GL/Spart) ready
  }
  const float sinv = 1.0f / sm.Spart[nsub * 16 + lm];

  // ---------------- MFMA GEMM, fully block-local ----------------------
  {
    const int sbase = nbase + lm - 1920;
    const int kstart = 2048 - (n0 + 32);   // multiple of 32
    const int iters = bn + 1;              // total 32-k steps for this tile

    f32x4 acc[4];
#pragma unroll
    for (int mt = 0; mt < 4; ++mt) acc[mt] = (f32x4){0.f, 0.f, 0.f, 0.f};

    union AF { unsigned short s[8]; bf16x8 v; };
    union BF { unsigned int u[4]; bf16x8 v; };
    AF a[3][4];
    BF bb[3];

// A-fragment from LDS: ro_b128 (quad-broadcast) + 32x ds_read_u16.
// a[SL][mt].s[j] = Wqb[ ro[k_+quad*8+j] + mt*16 + lm ]
#define LOAD_FRAGS(J_, SL) do {                                             \
    const int k_ = kstart + (kh + 2 * (J_)) * 32;                           \
    const int i0_ = k_ + quad * 8;                                          \
    unsigned short ro_[8];                                                  \
    *(uint4*)ro_ = *(const uint4*)&sm.ro[i0_];                              \
_Pragma("unroll")                                                           \
    for (int j_ = 0; j_ < 8; ++j_) {                                        \
      const int base_ = (int)ro_[j_] + lm;                                  \
      a[SL][0].s[j_] = sm.Wqb[base_ +  0];                                  \
      a[SL][1].s[j_] = sm.Wqb[base_ + 16];                                  \
      a[SL][2].s[j_] = sm.Wqb[base_ + 32];                                  \
      a[SL][3].s[j_] = sm.Wqb[base_ + 48];                                  \
    }                                                                       \
    const int s_ = sbase + k_ + quad * 8;                                   \
    const unsigned int* gb_ = (s_ & 1) ? (const unsigned int*)sm.GL1        \
                                       : (const unsigned int*)sm.GL0;       \
    const int off_ = s_ >> 1;                                               \
    bb[SL].u[0] = gb_[off_ + 0]; bb[SL].u[1] = gb_[off_ + 1];               \
    bb[SL].u[2] = gb_[off_ + 2]; bb[SL].u[3] = gb_[off_ + 3];               \
  } while (0)

#define MFMA4(SL) do {                                                      \
    acc[0] = __builtin_amdgcn_mfma_f32_16x16x32_bf16(a[SL][0].v, bb[SL].v, acc[0], 0, 0, 0); \
    acc[1] = __builtin_amdgcn_mfma_f32_16x16x32_bf16(a[SL][1].v, bb[SL].v, acc[1], 0, 0, 0); \
    acc[2] = __builtin_amdgcn_mfma_f32_16x16x32_bf16(a[SL][2].v, bb[SL].v, acc[2], 0, 0, 0); \
    acc[3] = __builtin_amdgcn_mfma_f32_16x16x32_bf16(a[SL][3].v, bb[SL].v, acc[3], 0, 0, 0); \
  } while (0)

    const int J = (iters > kh) ? ((iters - kh + 1) >> 1) : 0;  // wave-iters
    if (J > 0) {
      LOAD_FRAGS(0, 0);
      if (J > 1) LOAD_FRAGS(1, 1);
      int j = 0;
      while (true) {
        if (j + 2 < J) LOAD_FRAGS(j + 2, 2);
        MFMA4(0);
        if (++j >= J) break;
        if (j + 2 < J) LOAD_FRAGS(j + 2, 0);
        MFMA4(1);
        if (++j >= J) break;
        if (j + 2 < J) LOAD_FRAGS(j + 2, 1);
        MFMA4(2);
        if (++j >= J) break;
      }
    }
#undef LOAD_FRAGS
#undef MFMA4

    // reduce k-half 1 into k-half 0 via LDS (lane-contiguous, conflict-free)
    if (kh == 1) {
      float (*rd)[64] = nsub ? sm.red2 : sm.red;
#pragma unroll
      for (int mt = 0; mt < 4; ++mt)
#pragma unroll
        for (int r = 0; r < 4; ++r) rd[mt * 4 + r][lane] = acc[mt][r];
    }
    __syncthreads();
    if (kh == 0) {
      float (*rd)[64] = nsub ? sm.red2 : sm.red;
#pragma unroll
      for (int mt = 0; mt < 4; ++mt)
#pragma unroll
        for (int r = 0; r < 4; ++r) acc[mt][r] += rd[mt * 4 + r][lane];

      // epilogue: C/D layout col(s)=lm, row(c)=quad*4+r; NORMAL stores
#pragma unroll
      for (int mt = 0; mt < 4; ++mt) {
#pragma unroll
        for (int r = 0; r < 4; ++r) {
          const int c = mt * 16 + quad * 4 + r;
          P[((size_t)(b * 64 + c)) * LSEQ + nbase + lm] = __expf(acc[mt][r] * sinv);
        }
      }
    }
  }
}

// =====================================================================
// K2: chunk-hists + scan + fence-free emission, 1 (b,c) per block.
// P visible via the kernel boundary; reads served from L2/IC.
// =====================================================================
__global__ __launch_bounds__(256, 8) void k_scanemit(
    const int* __restrict__ idx, const float* __restrict__ P,
    const float* __restrict__ Wv, float* __restrict__ out) {
  __shared__ float Hs[NC][65];
  __shared__ float pl[4][64];
  __shared__ unsigned long long mk[4][64];

  const int bc = blockIdx.x;      // [0, 1024)
  const int b = bc >> 6;
  const int c = bc & 63;
  const int w = threadIdx.x >> 6;
  const int lane = threadIdx.x & 63;
  const int tid = threadIdx.x;

  const float* __restrict__ prow = P + (size_t)bc * LSEQ;
  const int* __restrict__ irow = idx + b * LSEQ;

  float p[8]; int ii[8];
#pragma unroll
  for (int r = 0; r < 8; ++r) {           // 16 independent coalesced loads
    const int ch = w * 8 + r;
    p[r] = prow[ch * 64 + lane];
    ii[r] = irow[ch * 64 + lane];
  }
  for (int i = tid; i < NC * 65; i += 256) ((float*)Hs)[i] = 0.f;
  __syncthreads();
#pragma unroll
  for (int r = 0; r < 8; ++r) atomicAdd(&Hs[w * 8 + r][ii[r]], p[r]);
  __syncthreads();

  // exclusive scan across chunks, per bin: 2 bins per pass (lane halves)
  const int hhalf = lane >> 5, l32 = lane & 31;
#pragma unroll
  for (int r = 0; r < 8; ++r) {
    const int v = w * 16 + r * 2 + hhalf;
    const float h = Hs[l32][v];
    float x = h;
#pragma unroll
    for (int d = 1; d < 32; d <<= 1) {
      float up = __shfl_up(x, d, 32);
      if (l32 >= d) x += up;
    }
    Hs[l32][v] = x - h;                   // exclusive
  }
  __syncthreads();

  const float wv = Wv[0];
#pragma unroll
  for (int r = 0; r < 8; ++r) {
    const int ch = w * 8 + r;
    unsigned long long em = __ballot(ii[r] == c);   // emission points
    if (em == 0ull) continue;                       // wave-uniform skip
    // per-chunk setup (wave-synchronous LDS, no fences):
    pl[w][lane] = p[r];                             // stage p
    mk[w][lane] = 0ull;
    atomicOr(&mk[w][ii[r]], 1ull << lane);          // bin <- source lanes
    float ps = p[r];                                // within-chunk prefix
#pragma unroll
    for (int d = 1; d < 64; d <<= 1) {
      float up = __shfl_up(ps, d);
      if (lane >= d) ps += up;
    }
    const float hbase = Hs[ch][lane];
    float zex = hbase;                              // Z_excl = sum_v Hs
#pragma unroll
    for (int d = 1; d < 64; d <<= 1) zex += __shfl_xor(zex, d);
    const unsigned long long myMask = mk[w][lane];
    while (em) {
      const int srel = __builtin_ctzll(em);
      em &= em - 1;
      unsigned long long mm = myMask &
          ((srel == 63) ? ~0ull : ((1ull << (srel + 1)) - 1ull));
      float B = hbase;                              // bin value at this t
      while (mm) { const int l = __builtin_ctzll(mm); mm &= mm - 1; B += pl[w][l]; }
      const float z = zex + __shfl(ps, srel);       // denominator
      out[((size_t)(b * LSEQ + ch * 64 + srel)) * 64 + lane] = wv * B / z;
    }
  }
}

extern "C" void kernel_launch(void* const* d_in, const int* in_sizes, int n_in,
                              void* d_out, int out_size, void* d_ws, size_t ws_size,
                              hipStream_t stream) {
  const int* idx     = (const int*)d_in[0];     // [16, 2048]
  const float* Wq    = (const float*)d_in[1];   // [64, 64]
  const float* Wv    = (const float*)d_in[2];   // [64, 64] (only [0,0] used)
  const float* v_emb = (const float*)d_in[3];   // [2048, 1]
  float* out = (float*)d_out;                   // [16, 2048, 64] fp32

  // workspace: [2048 f32 pad] | P[1024*2048] f32
  float* P = (float*)d_ws + LSEQ;

  k_gemm<<<dim3(NBLK), dim3(256), 0, stream>>>(idx, Wq, v_emb, P);
  k_scanemit<<<dim3(NBLK), dim3(256), 0, stream>>>(idx, P, Wv, out);
}

// Round 13
// 103.806 us; speedup vs baseline: 1.3117x; 1.0374x over previous
//
#include <hip/hip_runtime.h>

// B=16, L=2048, V=64.
// Algebraic reduction (e is one-hot):
//   E[d] = exp(v_emb[d]); S[t] = prefix_sum(E)[t]
//   F[b,c,s] = sum_{k<=s} E[s-k] * Wq[idx[b,k], c]            (causal Toeplitz GEMM)
//   P[b,c,s] = exp(F[b,c,s] / S[s])                           (softmax w/o max; scores tiny)
//   out[b,t,v] = Wv00 * (sum_{s<=t, idx[b,s]==v} P[b,c_t,s]) / (sum_{s<=t} P[b,c_t,s]),  c_t = idx[b,t]
//
// R29: R28's balanced permutation confirmed (-9.8us -> 107.7). Next: k1's
// A-gather has 2x redundancy — waves (nsub,kh) both gather the IDENTICAL
// 32x64 A-tile (A independent of s). Re-split waves as (mh,kh): mh halves M
// (cols 0-31 / 32-63) -> disjoint A halves (16 reads/wave/K-step), full N=32
// per wave via TWO B-fragments (8 reads, duplicated — B is cheap). Per
// K-step: 72 -> 48 LDS inst, unique gather halved (8320 -> 4160/CU). The
// verified 2-way kh reduction (red/red2, now keyed by mh) and epilogue
// layout preserved; 2nd B-frag = same GL buffer at +8 u32 (parity invariant
// under +16). k2 + permutation untouched. Predicted k1 ~27 -> ~20,
// total 107.7 -> 99-104, bank conflicts 2.48M -> ~1.3M.

#define LSEQ 2048
#define NB 16
#define NV 64
#define NC 32             // 32 chunks of 64
#define NBLK 1024

typedef __attribute__((ext_vector_type(8))) short bf16x8;
typedef __attribute__((ext_vector_type(4))) float f32x4;

__device__ __forceinline__ unsigned short f2bf(float f) {   // RNE float->bf16
  unsigned int u = __float_as_uint(f);
  return (unsigned short)((u + 0x7FFFu + ((u >> 16) & 1u)) >> 16);
}

// =====================================================================
// K1: setup (Wq/ro/E/S in LDS) + causal-Toeplitz MFMA GEMM, 1 32-col
// tile per block; CU-balanced tile permutation; (mh,kh) wave split.
// =====================================================================
__global__ __launch_bounds__(256, 4) void k_gemm(
    const int* __restrict__ idx, const float* __restrict__ Wq,
    const float* __restrict__ v_emb, float* __restrict__ P) {
  struct SMem {
    unsigned short Wqb[64 * 65];  // bf16 Wq, padded rows (8320B)
    unsigned short ro[2048];      // ro[i] = idx[b,2047-i]*65 (4096B)
    unsigned short GL0[2208];     // GL0[i] = (127<=i<2175) ? E[i-127] : 0
    unsigned short GL1[2176];     // GL1[i] = GLv(i+1)
    float red[16][64];
    float red2[16][64];
    float Spart[32];              // S[n0..n0+32) for this block's tile
    float swsum[4];
  };
  __shared__ SMem sm;

  const int bid = blockIdx.x;     // [0, 1024)
  const int tid = threadIdx.x;
  const int w = tid >> 6;
  const int lane = tid & 63;

  // CU-balanced permutation: CU = bid mod 256, slot v = bid>>8.
  // b = u&15, t = u>>4; bn = {t, 31-t, 32+t, 63-t}[v].
  // Per-CU work = (t+1)+(32-t)+(33+t)+(64-t) = 130 k-units, constant.
  const int u = bid & 255;
  const int v = bid >> 8;
  const int b = u & 15;
  const int t = u >> 4;
  const int bn = (v == 0) ? t : (v == 1) ? (31 - t) : (v == 2) ? (32 + t)
                                                              : (63 - t);
  const int n0 = bn * 32;
  const int quad = lane >> 4;
  const int lm = lane & 15;
  const int mh = w & 1;                    // M-half: cols mh*32 .. mh*32+31
  const int kh = w >> 1;                   // k-half 0 / 1

  // ---------------- setup: Wq -> LDS bf16, ro, E/S --------------------
  {
#pragma unroll
    for (int uu = 0; uu < 16; ++uu) {
      const int e = tid * 16 + uu;         // [0,4096)
      sm.Wqb[(e >> 6) * 65 + (e & 63)] = f2bf(Wq[e]);
    }
#pragma unroll
    for (int j = 0; j < 8; ++j) {
      const int tt = tid * 8 + j;
      sm.ro[2047 - tt] = (unsigned short)(idx[b * LSEQ + tt] * 65);
    }
    float ev[8], ps8[8];
    float tot = 0.f;
    const int t0 = tid * 8;
#pragma unroll
    for (int j = 0; j < 8; ++j) {
      const float e = expf(v_emb[t0 + j]);
      tot += e; ev[j] = e; ps8[j] = tot;
    }
    float ws = tot;                        // wave-inclusive scan of thread sums
#pragma unroll
    for (int d = 1; d < 64; d <<= 1) {
      float up = __shfl_up(ws, d);
      if (lane >= d) ws += up;
    }
    if (lane == 63) sm.swsum[w] = ws;
    __syncthreads();
    float wbase = 0.f;
#pragma unroll
    for (int k = 0; k < 4; ++k) if (k < w) wbase += sm.swsum[k];
    const float base = wbase + (ws - tot); // exclusive base for this thread
#pragma unroll
    for (int j = 0; j < 8; ++j) {
      const int d = t0 + j;
      const float Sv = base + ps8[j];
      if ((unsigned)(d - n0) < 32u) sm.Spart[d - n0] = Sv;
      const unsigned short bv = f2bf(ev[j]);
      sm.GL0[d + 127] = bv;                // GL0[i]=E[i-127]
      sm.GL1[d + 126] = bv;                // GL1[i]=E[i-126]
    }
    if (tid < 31) sm.GL0[96 + tid] = 0;    // zero [96,127)
    if (tid < 30) sm.GL1[96 + tid] = 0;    // zero [96,126)
    if (tid == 0) { sm.GL0[2175] = 0; sm.GL1[2174] = 0; sm.GL1[2175] = 0; }
    __syncthreads();                       // all LDS (Wqb/ro/GL/Spart) ready
  }

  // ---------------- MFMA GEMM, fully block-local ----------------------
  {
    const int sbase = n0 + lm - 1920;      // B col (s) base for this lane
    const int kstart = 2048 - (n0 + 32);   // multiple of 32
    const int iters = bn + 1;              // total 32-k steps for this tile
    const int cbase = mh * 32 + lm;        // A row (c) base for this lane

    f32x4 acc[2][2];                       // [mt2][ns]
#pragma unroll
    for (int mt = 0; mt < 2; ++mt)
#pragma unroll
      for (int ns = 0; ns < 2; ++ns) acc[mt][ns] = (f32x4){0.f, 0.f, 0.f, 0.f};

    union AF { unsigned short s[8]; bf16x8 v; };
    union BF { unsigned int u[4]; bf16x8 v; };
    AF a[3][2];
    BF bb[3][2];

// A-fragment (this wave's disjoint M-half) + two B-fragments (N=32).
// a[SL][mt2].s[j] = Wqb[ ro[k_+quad*8+j] + mh*32 + mt2*16 + lm ]
// bb[SL][ns]     = GL_parity[ (s_ + ns*16) ... ]  (parity invariant under +16)
#define LOAD_FRAGS(J_, SL) do {                                             \
    const int k_ = kstart + (kh + 2 * (J_)) * 32;                           \
    const int i0_ = k_ + quad * 8;                                          \
    unsigned short ro_[8];                                                  \
    *(uint4*)ro_ = *(const uint4*)&sm.ro[i0_];                              \
_Pragma("unroll")                                                           \
    for (int j_ = 0; j_ < 8; ++j_) {                                        \
      const int base_ = (int)ro_[j_] + cbase;                               \
      a[SL][0].s[j_] = sm.Wqb[base_ +  0];                                  \
      a[SL][1].s[j_] = sm.Wqb[base_ + 16];                                  \
    }                                                                       \
    const int s_ = sbase + k_ + quad * 8;                                   \
    const unsigned int* gb_ = (s_ & 1) ? (const unsigned int*)sm.GL1        \
                                       : (const unsigned int*)sm.GL0;       \
    const int off_ = s_ >> 1;                                               \
    bb[SL][0].u[0] = gb_[off_ + 0]; bb[SL][0].u[1] = gb_[off_ + 1];         \
    bb[SL][0].u[2] = gb_[off_ + 2]; bb[SL][0].u[3] = gb_[off_ + 3];         \
    bb[SL][1].u[0] = gb_[off_ + 8]; bb[SL][1].u[1] = gb_[off_ + 9];         \
    bb[SL][1].u[2] = gb_[off_ + 10]; bb[SL][1].u[3] = gb_[off_ + 11];       \
  } while (0)

#define MFMA8(SL) do {                                                      \
    acc[0][0] = __builtin_amdgcn_mfma_f32_16x16x32_bf16(a[SL][0].v, bb[SL][0].v, acc[0][0], 0, 0, 0); \
    acc[0][1] = __builtin_amdgcn_mfma_f32_16x16x32_bf16(a[SL][0].v, bb[SL][1].v, acc[0][1], 0, 0, 0); \
    acc[1][0] = __builtin_amdgcn_mfma_f32_16x16x32_bf16(a[SL][1].v, bb[SL][0].v, acc[1][0], 0, 0, 0); \
    acc[1][1] = __builtin_amdgcn_mfma_f32_16x16x32_bf16(a[SL][1].v, bb[SL][1].v, acc[1][1], 0, 0, 0); \
  } while (0)

    const int J = (iters > kh) ? ((iters - kh + 1) >> 1) : 0;  // wave-iters
    if (J > 0) {
      LOAD_FRAGS(0, 0);
      if (J > 1) LOAD_FRAGS(1, 1);
      int j = 0;
      while (true) {
        if (j + 2 < J) LOAD_FRAGS(j + 2, 2);
        MFMA8(0);
        if (++j >= J) break;
        if (j + 2 < J) LOAD_FRAGS(j + 2, 0);
        MFMA8(1);
        if (++j >= J) break;
        if (j + 2 < J) LOAD_FRAGS(j + 2, 1);
        MFMA8(2);
        if (++j >= J) break;
      }
    }
#undef LOAD_FRAGS
#undef MFMA8

    // reduce k-half 1 into k-half 0 via LDS (red keyed by mh; 16 rows/wave)
    if (kh == 1) {
      float (*rd)[64] = mh ? sm.red2 : sm.red;
#pragma unroll
      for (int mt = 0; mt < 2; ++mt)
#pragma unroll
        for (int ns = 0; ns < 2; ++ns)
#pragma unroll
          for (int r = 0; r < 4; ++r)
            rd[(mt * 2 + ns) * 4 + r][lane] = acc[mt][ns][r];
    }
    __syncthreads();
    if (kh == 0) {
      float (*rd)[64] = mh ? sm.red2 : sm.red;
#pragma unroll
      for (int mt = 0; mt < 2; ++mt)
#pragma unroll
        for (int ns = 0; ns < 2; ++ns)
#pragma unroll
          for (int r = 0; r < 4; ++r)
            acc[mt][ns][r] += rd[(mt * 2 + ns) * 4 + r][lane];

      // epilogue: C/D layout col(s)=lm, row(c)=quad*4+r; NORMAL stores
#pragma unroll
      for (int ns = 0; ns < 2; ++ns) {
        const float sinv = 1.0f / sm.Spart[ns * 16 + lm];
#pragma unroll
        for (int mt = 0; mt < 2; ++mt) {
#pragma unroll
          for (int r = 0; r < 4; ++r) {
            const int c = mh * 32 + mt * 16 + quad * 4 + r;
            P[((size_t)(b * 64 + c)) * LSEQ + n0 + ns * 16 + lm] =
                __expf(acc[mt][ns][r] * sinv);
          }
        }
      }
    }
  }
}

// =====================================================================
// K2: chunk-hists + scan + fence-free emission, 1 (b,c) per block.
// P visible via the kernel boundary; reads served from L2/IC.
// =====================================================================
__global__ __launch_bounds__(256, 8) void k_scanemit(
    const int* __restrict__ idx, const float* __restrict__ P,
    const float* __restrict__ Wv, float* __restrict__ out) {
  __shared__ float Hs[NC][65];
  __shared__ float pl[4][64];
  __shared__ unsigned long long mk[4][64];

  const int bc = blockIdx.x;      // [0, 1024)
  const int b = bc >> 6;
  const int c = bc & 63;
  const int w = threadIdx.x >> 6;
  const int lane = threadIdx.x & 63;
  const int tid = threadIdx.x;

  const float* __restrict__ prow = P + (size_t)bc * LSEQ;
  const int* __restrict__ irow = idx + b * LSEQ;

  float p[8]; int ii[8];
#pragma unroll
  for (int r = 0; r < 8; ++r) {           // 16 independent coalesced loads
    const int ch = w * 8 + r;
    p[r] = prow[ch * 64 + lane];
    ii[r] = irow[ch * 64 + lane];
  }
  for (int i = tid; i < NC * 65; i += 256) ((float*)Hs)[i] = 0.f;
  __syncthreads();
#pragma unroll
  for (int r = 0; r < 8; ++r) atomicAdd(&Hs[w * 8 + r][ii[r]], p[r]);
  __syncthreads();

  // exclusive scan across chunks, per bin: 2 bins per pass (lane halves)
  const int hhalf = lane >> 5, l32 = lane & 31;
#pragma unroll
  for (int r = 0; r < 8; ++r) {
    const int v = w * 16 + r * 2 + hhalf;
    const float h = Hs[l32][v];
    float x = h;
#pragma unroll
    for (int d = 1; d < 32; d <<= 1) {
      float up = __shfl_up(x, d, 32);
      if (l32 >= d) x += up;
    }
    Hs[l32][v] = x - h;                   // exclusive
  }
  __syncthreads();

  const float wv = Wv[0];
#pragma unroll
  for (int r = 0; r < 8; ++r) {
    const int ch = w * 8 + r;
    unsigned long long em = __ballot(ii[r] == c);   // emission points
    if (em == 0ull) continue;                       // wave-uniform skip
    // per-chunk setup (wave-synchronous LDS, no fences):
    pl[w][lane] = p[r];                             // stage p
    mk[w][lane] = 0ull;
    atomicOr(&mk[w][ii[r]], 1ull << lane);          // bin <- source lanes
    float ps = p[r];                                // within-chunk prefix
#pragma unroll
    for (int d = 1; d < 64; d <<= 1) {
      float up = __shfl_up(ps, d);
      if (lane >= d) ps += up;
    }
    const float hbase = Hs[ch][lane];
    float zex = hbase;                              // Z_excl = sum_v Hs
#pragma unroll
    for (int d = 1; d < 64; d <<= 1) zex += __shfl_xor(zex, d);
    const unsigned long long myMask = mk[w][lane];
    while (em) {
      const int srel = __builtin_ctzll(em);
      em &= em - 1;
      unsigned long long mm = myMask &
          ((srel == 63) ? ~0ull : ((1ull << (srel + 1)) - 1ull));
      float B = hbase;                              // bin value at this t
      while (mm) { const int l = __builtin_ctzll(mm); mm &= mm - 1; B += pl[w][l]; }
      const float z = zex + __shfl(ps, srel);       // denominator
      out[((size_t)(b * LSEQ + ch * 64 + srel)) * 64 + lane] = wv * B / z;
    }
  }
}

extern "C" void kernel_launch(void* const* d_in, const int* in_sizes, int n_in,
                              void* d_out, int out_size, void* d_ws, size_t ws_size,
                              hipStream_t stream) {
  const int* idx     = (const int*)d_in[0];     // [16, 2048]
  const float* Wq    = (const float*)d_in[1];   // [64, 64]
  const float* Wv    = (const float*)d_in[2];   // [64, 64] (only [0,0] used)
  const float* v_emb = (const float*)d_in[3];   // [2048, 1]
  float* out = (float*)d_out;                   // [16, 2048, 64] fp32

  // workspace: [2048 f32 pad] | P[1024*2048] f32
  float* P = (float*)d_ws + LSEQ;

  k_gemm<<<dim3(NBLK), dim3(256), 0, stream>>>(idx, Wq, v_emb, P);
  k_scanemit<<<dim3(NBLK), dim3(256), 0, stream>>>(idx, P, Wv, out);
}

// Round 14
// 101.309 us; speedup vs baseline: 1.3440x; 1.0246x over previous
//
#include <hip/hip_runtime.h>

// B=16, L=2048, V=64.
// Algebraic reduction (e is one-hot):
//   E[d] = exp(v_emb[d]); S[t] = prefix_sum(E)[t]
//   F[b,c,s] = sum_{k<=s} E[s-k] * Wq[idx[b,k], c]            (causal Toeplitz GEMM)
//   P[b,c,s] = exp(F[b,c,s] / S[s])                           (softmax w/o max; scores tiny)
//   out[b,t,v] = Wv00 * (sum_{s<=t, idx[b,s]==v} P[b,c_t,s]) / (sum_{s<=t} P[b,c_t,s]),  c_t = idx[b,t]
//
// R30: R29 on-prediction (103.8; A-dedup -3.9us). k1's gather is still the
// floor (~14us): each lane issues TWO ds_read_u16 per row (cols lm, lm+16).
// This round: pre-pair those columns at staging into u32 —
// WqP[row][p] = bf16(col c0) | bf16(col c1)<<16, (c0,c1)=(p+(p&16), +16) —
// so pair index mh*16+lm gives exactly the (mt0,mt1) columns. A-gather
// becomes 8x ds_read_b32 per lane per K-step (was 16x u16): same bytes,
// HALF the LDS instructions (the proven bottleneck; LDS cost is per-instr
// for width<=b32). WqP 8448B replaces Wqb 8320B; ro rescales to idx*33
// (max 2079, fits u16). Unpack ~1 v_perm per u32, absorbed by VALU slack.
// Permutation, (mh,kh) split, GL0/GL1, reduce, epilogue, k2: unchanged.
// Predicted k1 gather 14 -> ~8us; total 103.8 -> 97-101.

#define LSEQ 2048
#define NB 16
#define NV 64
#define NC 32             // 32 chunks of 64
#define NBLK 1024

typedef __attribute__((ext_vector_type(8))) short bf16x8;
typedef __attribute__((ext_vector_type(4))) float f32x4;

__device__ __forceinline__ unsigned short f2bf(float f) {   // RNE float->bf16
  unsigned int u = __float_as_uint(f);
  return (unsigned short)((u + 0x7FFFu + ((u >> 16) & 1u)) >> 16);
}

// =====================================================================
// K1: setup (WqP/ro/E/S in LDS) + causal-Toeplitz MFMA GEMM, 1 32-col
// tile per block; CU-balanced tile permutation; (mh,kh) wave split;
// column-paired u32 A-gather.
// =====================================================================
__global__ __launch_bounds__(256, 4) void k_gemm(
    const int* __restrict__ idx, const float* __restrict__ Wq,
    const float* __restrict__ v_emb, float* __restrict__ P) {
  struct SMem {
    unsigned int WqP[64 * 33];    // paired bf16 cols: [row][p]=(c0|c1<<16), 8448B
    unsigned short ro[2048];      // ro[i] = idx[b,2047-i]*33 (4096B)
    unsigned short GL0[2208];     // GL0[i] = (127<=i<2175) ? E[i-127] : 0
    unsigned short GL1[2176];     // GL1[i] = GLv(i+1)
    float red[16][64];
    float red2[16][64];
    float Spart[32];              // S[n0..n0+32) for this block's tile
    float swsum[4];
  };
  __shared__ SMem sm;

  const int bid = blockIdx.x;     // [0, 1024)
  const int tid = threadIdx.x;
  const int w = tid >> 6;
  const int lane = tid & 63;

  // CU-balanced permutation: CU = bid mod 256, slot v = bid>>8.
  // b = u&15, t = u>>4; bn = {t, 31-t, 32+t, 63-t}[v].
  // Per-CU work = (t+1)+(32-t)+(33+t)+(64-t) = 130 k-units, constant.
  const int u = bid & 255;
  const int v = bid >> 8;
  const int b = u & 15;
  const int t = u >> 4;
  const int bn = (v == 0) ? t : (v == 1) ? (31 - t) : (v == 2) ? (32 + t)
                                                              : (63 - t);
  const int n0 = bn * 32;
  const int quad = lane >> 4;
  const int lm = lane & 15;
  const int mh = w & 1;                    // M-half: cols mh*32 .. mh*32+31
  const int kh = w >> 1;                   // k-half 0 / 1

  // ---------------- setup: Wq -> LDS paired bf16, ro, E/S -------------
  {
    // WqP staging: 2048 u32, 8 per thread; (c0,c1) = (p+(p&16), +16)
#pragma unroll
    for (int uu = 0; uu < 8; ++uu) {
      const int e = tid * 8 + uu;          // [0,2048); row const per thread
      const int row = e >> 5;
      const int p = e & 31;
      const int c0 = p + (p & 16);
      sm.WqP[row * 33 + p] =
          (unsigned int)f2bf(Wq[row * 64 + c0]) |
          ((unsigned int)f2bf(Wq[row * 64 + c0 + 16]) << 16);
    }
#pragma unroll
    for (int j = 0; j < 8; ++j) {
      const int tt = tid * 8 + j;
      sm.ro[2047 - tt] = (unsigned short)(idx[b * LSEQ + tt] * 33);
    }
    float ev[8], ps8[8];
    float tot = 0.f;
    const int t0 = tid * 8;
#pragma unroll
    for (int j = 0; j < 8; ++j) {
      const float e = expf(v_emb[t0 + j]);
      tot += e; ev[j] = e; ps8[j] = tot;
    }
    float ws = tot;                        // wave-inclusive scan of thread sums
#pragma unroll
    for (int d = 1; d < 64; d <<= 1) {
      float up = __shfl_up(ws, d);
      if (lane >= d) ws += up;
    }
    if (lane == 63) sm.swsum[w] = ws;
    __syncthreads();
    float wbase = 0.f;
#pragma unroll
    for (int k = 0; k < 4; ++k) if (k < w) wbase += sm.swsum[k];
    const float base = wbase + (ws - tot); // exclusive base for this thread
#pragma unroll
    for (int j = 0; j < 8; ++j) {
      const int d = t0 + j;
      const float Sv = base + ps8[j];
      if ((unsigned)(d - n0) < 32u) sm.Spart[d - n0] = Sv;
      const unsigned short bv = f2bf(ev[j]);
      sm.GL0[d + 127] = bv;                // GL0[i]=E[i-127]
      sm.GL1[d + 126] = bv;                // GL1[i]=E[i-126]
    }
    if (tid < 31) sm.GL0[96 + tid] = 0;    // zero [96,127)
    if (tid < 30) sm.GL1[96 + tid] = 0;    // zero [96,126)
    if (tid == 0) { sm.GL0[2175] = 0; sm.GL1[2174] = 0; sm.GL1[2175] = 0; }
    __syncthreads();                       // all LDS (WqP/ro/GL/Spart) ready
  }

  // ---------------- MFMA GEMM, fully block-local ----------------------
  {
    const int sbase = n0 + lm - 1920;      // B col (s) base for this lane
    const int kstart = 2048 - (n0 + 32);   // multiple of 32
    const int iters = bn + 1;              // total 32-k steps for this tile
    const int pbase = mh * 16 + lm;        // pair index for this lane

    f32x4 acc[2][2];                       // [mt2][ns]
#pragma unroll
    for (int mt = 0; mt < 2; ++mt)
#pragma unroll
      for (int ns = 0; ns < 2; ++ns) acc[mt][ns] = (f32x4){0.f, 0.f, 0.f, 0.f};

    union AF { unsigned short s[8]; bf16x8 v; };
    union BF { unsigned int u[4]; bf16x8 v; };
    AF a[3][2];
    BF bb[3][2];

// A-fragments via paired u32 gather: one ds_read_b32 per row covers both
// mt columns. a[SL][0].s[j]=lo16, a[SL][1].s[j]=hi16.
#define LOAD_FRAGS(J_, SL) do {                                             \
    const int k_ = kstart + (kh + 2 * (J_)) * 32;                           \
    const int i0_ = k_ + quad * 8;                                          \
    unsigned short ro_[8];                                                  \
    *(uint4*)ro_ = *(const uint4*)&sm.ro[i0_];                              \
_Pragma("unroll")                                                           \
    for (int j_ = 0; j_ < 8; ++j_) {                                        \
      const unsigned int r_ = sm.WqP[(int)ro_[j_] + pbase];                 \
      a[SL][0].s[j_] = (unsigned short)r_;                                  \
      a[SL][1].s[j_] = (unsigned short)(r_ >> 16);                          \
    }                                                                       \
    const int s_ = sbase + k_ + quad * 8;                                   \
    const unsigned int* gb_ = (s_ & 1) ? (const unsigned int*)sm.GL1        \
                                       : (const unsigned int*)sm.GL0;       \
    const int off_ = s_ >> 1;                                               \
    bb[SL][0].u[0] = gb_[off_ + 0]; bb[SL][0].u[1] = gb_[off_ + 1];         \
    bb[SL][0].u[2] = gb_[off_ + 2]; bb[SL][0].u[3] = gb_[off_ + 3];         \
    bb[SL][1].u[0] = gb_[off_ + 8]; bb[SL][1].u[1] = gb_[off_ + 9];         \
    bb[SL][1].u[2] = gb_[off_ + 10]; bb[SL][1].u[3] = gb_[off_ + 11];       \
  } while (0)

#define MFMA8(SL) do {                                                      \
    acc[0][0] = __builtin_amdgcn_mfma_f32_16x16x32_bf16(a[SL][0].v, bb[SL][0].v, acc[0][0], 0, 0, 0); \
    acc[0][1] = __builtin_amdgcn_mfma_f32_16x16x32_bf16(a[SL][0].v, bb[SL][1].v, acc[0][1], 0, 0, 0); \
    acc[1][0] = __builtin_amdgcn_mfma_f32_16x16x32_bf16(a[SL][1].v, bb[SL][0].v, acc[1][0], 0, 0, 0); \
    acc[1][1] = __builtin_amdgcn_mfma_f32_16x16x32_bf16(a[SL][1].v, bb[SL][1].v, acc[1][1], 0, 0, 0); \
  } while (0)

    const int J = (iters > kh) ? ((iters - kh + 1) >> 1) : 0;  // wave-iters
    if (J > 0) {
      LOAD_FRAGS(0, 0);
      if (J > 1) LOAD_FRAGS(1, 1);
      int j = 0;
      while (true) {
        if (j + 2 < J) LOAD_FRAGS(j + 2, 2);
        MFMA8(0);
        if (++j >= J) break;
        if (j + 2 < J) LOAD_FRAGS(j + 2, 0);
        MFMA8(1);
        if (++j >= J) break;
        if (j + 2 < J) LOAD_FRAGS(j + 2, 1);
        MFMA8(2);
        if (++j >= J) break;
      }
    }
#undef LOAD_FRAGS
#undef MFMA8

    // reduce k-half 1 into k-half 0 via LDS (red keyed by mh; 16 rows/wave)
    if (kh == 1) {
      float (*rd)[64] = mh ? sm.red2 : sm.red;
#pragma unroll
      for (int mt = 0; mt < 2; ++mt)
#pragma unroll
        for (int ns = 0; ns < 2; ++ns)
#pragma unroll
          for (int r = 0; r < 4; ++r)
            rd[(mt * 2 + ns) * 4 + r][lane] = acc[mt][ns][r];
    }
    __syncthreads();
    if (kh == 0) {
      float (*rd)[64] = mh ? sm.red2 : sm.red;
#pragma unroll
      for (int mt = 0; mt < 2; ++mt)
#pragma unroll
        for (int ns = 0; ns < 2; ++ns)
#pragma unroll
          for (int r = 0; r < 4; ++r)
            acc[mt][ns][r] += rd[(mt * 2 + ns) * 4 + r][lane];

      // epilogue: C/D layout col(s)=lm, row(c)=quad*4+r; NORMAL stores
#pragma unroll
      for (int ns = 0; ns < 2; ++ns) {
        const float sinv = 1.0f / sm.Spart[ns * 16 + lm];
#pragma unroll
        for (int mt = 0; mt < 2; ++mt) {
#pragma unroll
          for (int r = 0; r < 4; ++r) {
            const int c = mh * 32 + mt * 16 + quad * 4 + r;
            P[((size_t)(b * 64 + c)) * LSEQ + n0 + ns * 16 + lm] =
                __expf(acc[mt][ns][r] * sinv);
          }
        }
      }
    }
  }
}

// =====================================================================
// K2: chunk-hists + scan + fence-free emission, 1 (b,c) per block.
// P visible via the kernel boundary; reads served from L2/IC.
// =====================================================================
__global__ __launch_bounds__(256, 8) void k_scanemit(
    const int* __restrict__ idx, const float* __restrict__ P,
    const float* __restrict__ Wv, float* __restrict__ out) {
  __shared__ float Hs[NC][65];
  __shared__ float pl[4][64];
  __shared__ unsigned long long mk[4][64];

  const int bc = blockIdx.x;      // [0, 1024)
  const int b = bc >> 6;
  const int c = bc & 63;
  const int w = threadIdx.x >> 6;
  const int lane = threadIdx.x & 63;
  const int tid = threadIdx.x;

  const float* __restrict__ prow = P + (size_t)bc * LSEQ;
  const int* __restrict__ irow = idx + b * LSEQ;

  float p[8]; int ii[8];
#pragma unroll
  for (int r = 0; r < 8; ++r) {           // 16 independent coalesced loads
    const int ch = w * 8 + r;
    p[r] = prow[ch * 64 + lane];
    ii[r] = irow[ch * 64 + lane];
  }
  for (int i = tid; i < NC * 65; i += 256) ((float*)Hs)[i] = 0.f;
  __syncthreads();
#pragma unroll
  for (int r = 0; r < 8; ++r) atomicAdd(&Hs[w * 8 + r][ii[r]], p[r]);
  __syncthreads();

  // exclusive scan across chunks, per bin: 2 bins per pass (lane halves)
  const int hhalf = lane >> 5, l32 = lane & 31;
#pragma unroll
  for (int r = 0; r < 8; ++r) {
    const int v = w * 16 + r * 2 + hhalf;
    const float h = Hs[l32][v];
    float x = h;
#pragma unroll
    for (int d = 1; d < 32; d <<= 1) {
      float up = __shfl_up(x, d, 32);
      if (l32 >= d) x += up;
    }
    Hs[l32][v] = x - h;                   // exclusive
  }
  __syncthreads();

  const float wv = Wv[0];
#pragma unroll
  for (int r = 0; r < 8; ++r) {
    const int ch = w * 8 + r;
    unsigned long long em = __ballot(ii[r] == c);   // emission points
    if (em == 0ull) continue;                       // wave-uniform skip
    // per-chunk setup (wave-synchronous LDS, no fences):
    pl[w][lane] = p[r];                             // stage p
    mk[w][lane] = 0ull;
    atomicOr(&mk[w][ii[r]], 1ull << lane);          // bin <- source lanes
    float ps = p[r];                                // within-chunk prefix
#pragma unroll
    for (int d = 1; d < 64; d <<= 1) {
      float up = __shfl_up(ps, d);
      if (lane >= d) ps += up;
    }
    const float hbase = Hs[ch][lane];
    float zex = hbase;                              // Z_excl = sum_v Hs
#pragma unroll
    for (int d = 1; d < 64; d <<= 1) zex += __shfl_xor(zex, d);
    const unsigned long long myMask = mk[w][lane];
    while (em) {
      const int srel = __builtin_ctzll(em);
      em &= em - 1;
      unsigned long long mm = myMask &
          ((srel == 63) ? ~0ull : ((1ull << (srel + 1)) - 1ull));
      float B = hbase;                              // bin value at this t
      while (mm) { const int l = __builtin_ctzll(mm); mm &= mm - 1; B += pl[w][l]; }
      const float z = zex + __shfl(ps, srel);       // denominator
      out[((size_t)(b * LSEQ + ch * 64 + srel)) * 64 + lane] = wv * B / z;
    }
  }
}

extern "C" void kernel_launch(void* const* d_in, const int* in_sizes, int n_in,
                              void* d_out, int out_size, void* d_ws, size_t ws_size,
                              hipStream_t stream) {
  const int* idx     = (const int*)d_in[0];     // [16, 2048]
  const float* Wq    = (const float*)d_in[1];   // [64, 64]
  const float* Wv    = (const float*)d_in[2];   // [64, 64] (only [0,0] used)
  const float* v_emb = (const float*)d_in[3];   // [2048, 1]
  float* out = (float*)d_out;                   // [16, 2048, 64] fp32

  // workspace: [2048 f32 pad] | P[1024*2048] f32
  float* P = (float*)d_ws + LSEQ;

  k_gemm<<<dim3(NBLK), dim3(256), 0, stream>>>(idx, Wq, v_emb, P);
  k_scanemit<<<dim3(NBLK), dim3(256), 0, stream>>>(idx, P, Wv, out);
}